// Round 2
// baseline (266.459 us; speedup 1.0000x reference)
//
#include <hip/hip_runtime.h>
#include <hip/hip_bf16.h>

#define BS  4
#define SEQ 4096
#define DK  128

// p = exp(s_raw / sqrt(128)) = exp2(C1_SCALE * s_raw).  C1_SCALE is folded
// into the bf16 cast of Q (replaces the cast rounding, does not add one), so
// the MFMA output is already in log2 domain: p = exp2(s).
#define C1_SCALE (1.4426950408889634f / 11.313708498984761f)

typedef __attribute__((ext_vector_type(8))) short bf16x8;
typedef __attribute__((ext_vector_type(4))) float f32x4;
typedef unsigned short ushort_t;

__device__ inline unsigned pk_bf16(float a, float b) {
    __hip_bfloat162 h = __float22bfloat162_rn(make_float2(a, b));
    union { __hip_bfloat162 h2; unsigned u; } cv;
    cv.h2 = h;
    return cv.u;
}

__device__ inline bf16x8 pk8(float4 a, float4 b) {
    union { bf16x8 v; unsigned u[4]; } r;
    r.u[0] = pk_bf16(a.x, a.y);
    r.u[1] = pk_bf16(a.z, a.w);
    r.u[2] = pk_bf16(b.x, b.y);
    r.u[3] = pk_bf16(b.z, b.w);
    return r.v;
}

// ---------------------------------------------------------------------------
// Swizzled-row bf16 cast of Q (x C1_SCALE) and K: row r (256 B = 16 atoms of
// 16 B), atom a stored at position a ^ (r & 15). Fragment reads use atom
// ((c*4+quad) ^ ln) -> conflict-free gathers.
// ---------------------------------------------------------------------------
__global__ __launch_bounds__(256) void cast_qk_sw(
    const float* __restrict__ Q, const float* __restrict__ K,
    ushort_t* __restrict__ Qb, ushort_t* __restrict__ Kb)
{
    const int g = blockIdx.x * 256 + threadIdx.x;   // atom id
    const int q = g >> 4, ap = g & 15;
    const int a = ap ^ (q & 15);
    const float* src = Q + (size_t)q * DK + a * 8;
    float4 x = *(const float4*)src, y = *(const float4*)(src + 4);
    x.x *= C1_SCALE; x.y *= C1_SCALE; x.z *= C1_SCALE; x.w *= C1_SCALE;
    y.x *= C1_SCALE; y.y *= C1_SCALE; y.z *= C1_SCALE; y.w *= C1_SCALE;
    *(bf16x8*)(Qb + (size_t)g * 8) = pk8(x, y);
    src = K + (size_t)q * DK + a * 8;
    float4 x2 = *(const float4*)src, y2 = *(const float4*)(src + 4);
    *(bf16x8*)(Kb + (size_t)g * 8) = pk8(x2, y2);
}

// ---------------------------------------------------------------------------
// Pass 1: l[b,k] partials = sum_q exp(s_qk).  No P materialization.
// grid (kt=32, qs=8, b=4) = 1024 blocks, 256 thr, no LDS, no barriers.
// K rows stationary in regs (A-operand); Q streamed from global (L2).
// ---------------------------------------------------------------------------
__global__ __launch_bounds__(256) void sdpa_lsum(
    const ushort_t* __restrict__ Qb, const ushort_t* __restrict__ Kb,
    float* __restrict__ lp)
{
    const int kt = blockIdx.x, qs = blockIdx.y, b = blockIdx.z;
    const int tid = threadIdx.x;
    const int w = tid >> 6, lane = tid & 63, ln = lane & 15, quad = lane >> 4;

    bf16x8 ka[2][4];
#pragma unroll
    for (int mt = 0; mt < 2; ++mt)
#pragma unroll
        for (int c = 0; c < 4; ++c)
            ka[mt][c] = *(const bf16x8*)(Kb +
                ((size_t)(b * SEQ) + kt * 128 + w * 32 + mt * 16 + ln) * DK +
                (((c * 4 + quad) ^ ln) * 8));

    float ls[2][4] = {};
    const ushort_t* qbase = Qb + ((size_t)(b * SEQ) + qs * 512 + ln) * DK;
    bf16x8 qf0[2][4], qf1[2][4];

#define L_PRE(QF, IT)                                                          \
    {                                                                          \
        _Pragma("unroll")                                                      \
        for (int nt = 0; nt < 2; ++nt)                                         \
            _Pragma("unroll")                                                  \
            for (int c = 0; c < 4; ++c)                                        \
                QF[nt][c] = *(const bf16x8*)(qbase +                           \
                    ((size_t)((IT) * 32 + nt * 16)) * DK +                     \
                    (((c * 4 + quad) ^ ln) * 8));                              \
    }
#define L_CMP(QF)                                                              \
    {                                                                          \
        _Pragma("unroll")                                                      \
        for (int mt = 0; mt < 2; ++mt)                                         \
            _Pragma("unroll")                                                  \
            for (int nt = 0; nt < 2; ++nt) {                                   \
                f32x4 s = {0.f, 0.f, 0.f, 0.f};                                \
                __builtin_amdgcn_s_setprio(1);                                 \
                _Pragma("unroll")                                              \
                for (int c = 0; c < 4; ++c)                                    \
                    s = __builtin_amdgcn_mfma_f32_16x16x32_bf16(               \
                        ka[mt][c], QF[nt][c], s, 0, 0, 0);                     \
                __builtin_amdgcn_s_setprio(0);                                 \
                _Pragma("unroll")                                              \
                for (int r = 0; r < 4; ++r)                                    \
                    ls[mt][r] += __builtin_amdgcn_exp2f(s[r]);                 \
            }                                                                  \
    }
    L_PRE(qf0, 0)
    for (int ii = 0; ii < 8; ++ii) {
        const int i0 = 2 * ii;
        L_PRE(qf1, i0 + 1)
        L_CMP(qf0)
        if (ii < 7) L_PRE(qf0, i0 + 2)
        L_CMP(qf1)
    }
#undef L_PRE
#undef L_CMP

#pragma unroll
    for (int mt = 0; mt < 2; ++mt)
#pragma unroll
        for (int r = 0; r < 4; ++r) {
            float vv = ls[mt][r];
            vv += __shfl_xor(vv, 1);
            vv += __shfl_xor(vv, 2);
            vv += __shfl_xor(vv, 4);
            vv += __shfl_xor(vv, 8);
            ls[mt][r] = vv;
        }
    if (ln < 8) {
        int k = kt * 128 + w * 32 + (ln >> 2) * 16 + quad * 4 + (ln & 3);
        lp[((size_t)(qs * BS + b)) * SEQ + k] = ls[ln >> 2][ln & 3];
    }
}

// ---------------------------------------------------------------------------
// VbT[b][d][k] = bf16( V[b][k][d] / l[b][k] ), l = sum of 8 qs-partials.
// ---------------------------------------------------------------------------
__global__ __launch_bounds__(256) void vb_transpose(
    const float* __restrict__ V, const float* __restrict__ lp,
    ushort_t* __restrict__ VbT)
{
    __shared__ float Vl[64][132];
    __shared__ float Wl[64];

    const int kt = blockIdx.x, b = blockIdx.y;
    const int tid = threadIdx.x;
    const int k0 = kt * 64;
    {
        int r = tid >> 2, sg = tid & 3;
        const float* src = V + ((size_t)(b * SEQ) + k0 + r) * DK + sg * 32;
#pragma unroll
        for (int i = 0; i < 8; ++i)
            *(float4*)&Vl[r][sg * 32 + i * 4] = *(const float4*)(src + i * 4);
    }
    if (tid < 64) {
        float s = 0.f;
#pragma unroll
        for (int qs = 0; qs < 8; ++qs)
            s += lp[((size_t)(qs * BS + b)) * SEQ + k0 + tid];
        Wl[tid] = 1.0f / s;
    }
    __syncthreads();

    const int d = tid >> 1, kh = tid & 1;
    unsigned u[16];
#pragma unroll
    for (int j = 0; j < 16; ++j) {
        int row = kh * 32 + j * 2;
        u[j] = pk_bf16(Vl[row][d] * Wl[row], Vl[row + 1][d] * Wl[row + 1]);
    }
    ushort_t* dst = VbT + ((size_t)(b * DK) + d) * SEQ + k0 + kh * 32;
#pragma unroll
    for (int i = 0; i < 4; ++i) {
        uint4 t4; t4.x = u[i*4]; t4.y = u[i*4+1]; t4.z = u[i*4+2]; t4.w = u[i*4+3];
        *(uint4*)(dst + i * 8) = t4;
    }
}

// ---------------------------------------------------------------------------
// Pass 2: O_partial[ks] = exp(QK^T) . V'  — BARRIER-FREE.
// Each wave owns a private 16-q strip (block = 4 waves x 16 q = 64 q) and
// iterates the full 1024-k split itself.  The QK C-frag -> PV A-frag
// relayout bounces through a 2 KB wave-private LDS scratch (same-wave
// write->read, lgkmcnt-ordered, NO __syncthreads anywhere in the loop).
// K/V frags stream from L2 (512 KB slice, XCD-pinned via blockIdx.x).
// LDS rows are 128 B with atom^(ln&7) swizzle -> uniform 8 dw/bank (the
// wave64 b128 floor, i.e. conflict-free).
// grid (x=16 (ks,b), y=64 qt), 256 thr, 8 KB LDS.
// ---------------------------------------------------------------------------
__global__ __launch_bounds__(256, 2) void sdpa_out(
    const ushort_t* __restrict__ Qb, const ushort_t* __restrict__ Kb,
    const ushort_t* __restrict__ VbT,
    float* __restrict__ Op, float* __restrict__ O, int use_partial)
{
    __shared__ ushort_t Pt[4][1024];   // per-wave [16 q][64 k] bf16, swizzled

    const int g  = blockIdx.x;
    const int qt = blockIdx.y;
    const int ks = g >> 2, b = g & 3;
    const int tid = threadIdx.x;
    const int w = tid >> 6, lane = tid & 63, ln = lane & 15, quad = lane >> 4;

    // stationary Q: rows qt*64 + w*16 + (0..15)
    bf16x8 qa[4];
#pragma unroll
    for (int c = 0; c < 4; ++c)
        qa[c] = *(const bf16x8*)(Qb +
            ((size_t)(b * SEQ) + qt * 64 + w * 16 + ln) * DK +
            (((c * 4 + quad) ^ ln) * 8));

    f32x4 acc[8];
#pragma unroll
    for (int i = 0; i < 8; ++i) acc[i] = (f32x4){0.f, 0.f, 0.f, 0.f};

    const ushort_t* kfp = Kb + ((size_t)(b * SEQ) + ks * 1024 + ln) * DK;
    const ushort_t* vfp = VbT + ((size_t)(b * DK) + ln) * SEQ + ks * 1024 + quad * 8;

    bf16x8 ka[2][4], vf[8];

#define LOADK(NIT, NH)                                                         \
    {                                                                          \
        _Pragma("unroll")                                                      \
        for (int kt2 = 0; kt2 < 2; ++kt2)                                      \
            _Pragma("unroll")                                                  \
            for (int c = 0; c < 4; ++c)                                        \
                ka[kt2][c] = *(const bf16x8*)(kfp +                            \
                    (size_t)((NIT) * 64 + (NH) * 32 + kt2 * 16) * DK +         \
                    (((c * 4 + quad) ^ ln) * 8));                              \
    }
#define LOADV(NIT, NH)                                                         \
    {                                                                          \
        _Pragma("unroll")                                                      \
        for (int dt = 0; dt < 8; ++dt)                                         \
            vf[dt] = *(const bf16x8*)(vfp + (size_t)dt * 16 * SEQ +            \
                                      (NIT) * 64 + (NH) * 32);                 \
    }
// one half-iteration: 32 k x 16 q QK (8 MFMA), exp/pack, private LDS bounce,
// 32 k x 16 q x 128 d PV (8 MFMA).  Next half's K issued right after QK
// consumes ka; next half's V issued right after PV consumes vf.
#define HALF(H, NIT, NH)                                                       \
    {                                                                          \
        f32x4 s0 = {0.f, 0.f, 0.f, 0.f}, s1 = {0.f, 0.f, 0.f, 0.f};           \
        __builtin_amdgcn_s_setprio(1);                                         \
        _Pragma("unroll")                                                      \
        for (int c = 0; c < 4; ++c)                                            \
            s0 = __builtin_amdgcn_mfma_f32_16x16x32_bf16(ka[0][c], qa[c], s0, 0, 0, 0); \
        _Pragma("unroll")                                                      \
        for (int c = 0; c < 4; ++c)                                            \
            s1 = __builtin_amdgcn_mfma_f32_16x16x32_bf16(ka[1][c], qa[c], s1, 0, 0, 0); \
        __builtin_amdgcn_s_setprio(0);                                         \
        LOADK(NIT, NH)                                                         \
        uint2 p0, p1;                                                          \
        p0.x = pk_bf16(__builtin_amdgcn_exp2f(s0[0]), __builtin_amdgcn_exp2f(s0[1])); \
        p0.y = pk_bf16(__builtin_amdgcn_exp2f(s0[2]), __builtin_amdgcn_exp2f(s0[3])); \
        p1.x = pk_bf16(__builtin_amdgcn_exp2f(s1[0]), __builtin_amdgcn_exp2f(s1[1])); \
        p1.y = pk_bf16(__builtin_amdgcn_exp2f(s1[2]), __builtin_amdgcn_exp2f(s1[3])); \
        *(uint2*)&Pt[w][ln * 64 + ((((H) * 4 + 0 + (quad >> 1)) ^ (ln & 7)) * 8) + (quad & 1) * 4] = p0; \
        *(uint2*)&Pt[w][ln * 64 + ((((H) * 4 + 2 + (quad >> 1)) ^ (ln & 7)) * 8) + (quad & 1) * 4] = p1; \
        bf16x8 pa = *(const bf16x8*)&Pt[w][ln * 64 + ((((H) * 4 + quad) ^ (ln & 7)) * 8)]; \
        __builtin_amdgcn_s_setprio(1);                                         \
        _Pragma("unroll")                                                      \
        for (int dt = 0; dt < 8; ++dt)                                         \
            acc[dt] = __builtin_amdgcn_mfma_f32_16x16x32_bf16(pa, vf[dt], acc[dt], 0, 0, 0); \
        __builtin_amdgcn_s_setprio(0);                                         \
        LOADV(NIT, NH)                                                         \
    }

    LOADK(0, 0)
    LOADV(0, 0)
    for (int it = 0; it < 16; ++it) {
        HALF(0, it, 1)
        const int nx = (it < 15) ? it + 1 : 15;
        HALF(1, nx, 0)
    }
#undef LOADK
#undef LOADV
#undef HALF

    if (use_partial) {
        float* dst = Op + (size_t)ks * ((size_t)BS * SEQ * DK) +
                     ((size_t)(b * SEQ) + qt * 64 + w * 16 + quad * 4) * DK + ln;
#pragma unroll
        for (int dt = 0; dt < 8; ++dt)
#pragma unroll
            for (int r = 0; r < 4; ++r)
                dst[(size_t)r * DK + dt * 16] = acc[dt][r];
    } else {
#pragma unroll
        for (int dt = 0; dt < 8; ++dt)
#pragma unroll
            for (int r = 0; r < 4; ++r)
                atomicAdd(&O[((size_t)(b * SEQ) + qt * 64 + w * 16 + quad * 4 + r) * DK +
                             dt * 16 + ln], acc[dt][r]);
    }
}

// ---------------------------------------------------------------------------
// reduce4: O = sum of 4 k-split partials (float4 per thread).
// ---------------------------------------------------------------------------
__global__ __launch_bounds__(256) void reduce4(
    const float* __restrict__ Op, float* __restrict__ O)
{
    const size_t N = (size_t)BS * SEQ * DK;
    size_t i = ((size_t)blockIdx.x * 256 + threadIdx.x) * 4;
    float4 a0 = *(const float4*)(Op + i);
    float4 a1 = *(const float4*)(Op + N + i);
    float4 a2 = *(const float4*)(Op + 2 * N + i);
    float4 a3 = *(const float4*)(Op + 3 * N + i);
    float4 r;
    r.x = a0.x + a1.x + a2.x + a3.x;
    r.y = a0.y + a1.y + a2.y + a3.y;
    r.z = a0.z + a1.z + a2.z + a3.z;
    r.w = a0.w + a1.w + a2.w + a3.w;
    *(float4*)(O + i) = r;
}

extern "C" void kernel_launch(void* const* d_in, const int* in_sizes, int n_in,
                              void* d_out, int out_size, void* d_ws, size_t ws_size,
                              hipStream_t stream) {
    const float* q = (const float*)d_in[0];
    const float* k = (const float*)d_in[1];
    const float* v = (const float*)d_in[2];
    float* out = (float*)d_out;

    const size_t QKV = (size_t)BS * SEQ * DK;           // 2 M elements
    float*    lp  = (float*)d_ws;                       // 512 KB used
    ushort_t* Qb  = (ushort_t*)((char*)d_ws + (1 << 20));
    ushort_t* Kb  = Qb + QKV;
    ushort_t* VbT = Kb + QKV;
    float*    Op  = (float*)(VbT + QKV);                // 33.6 MB (4 k-splits)

    const size_t need_p = (1u << 20) + 3 * QKV * 2 + 4 * QKV * sizeof(float);

    cast_qk_sw<<<dim3(BS * SEQ * 16 / 256), 256, 0, stream>>>(q, k, Qb, Kb);
    sdpa_lsum  <<<dim3(32, 8, 4), 256, 0, stream>>>(Qb, Kb, lp);
    vb_transpose<<<dim3(64, 4),   256, 0, stream>>>(v, lp, VbT);

    if (ws_size >= need_p) {
        sdpa_out<<<dim3(16, 64), 256, 0, stream>>>(Qb, Kb, VbT, Op, out, 1);
        reduce4 <<<dim3(BS * SEQ * DK / 4 / 256), 256, 0, stream>>>(Op, out);
    } else {
        hipMemsetAsync(out, 0, QKV * sizeof(float), stream);
        sdpa_out<<<dim3(16, 64), 256, 0, stream>>>(Qb, Kb, VbT, nullptr, out, 0);
    }
}

// Round 3
// 172.420 us; speedup vs baseline: 1.5454x; 1.5454x over previous
//
#include <hip/hip_runtime.h>
#include <hip/hip_bf16.h>

#define BS  4
#define SEQ 4096
#define DK  128

// p = exp(s_raw / sqrt(128)) = exp2(C1_SCALE * s_raw).  C1_SCALE is folded
// into the bf16 cast of Q (replaces the cast rounding, does not add one), so
// the MFMA output is already in log2 domain: p = exp2(s).
#define C1_SCALE (1.4426950408889634f / 11.313708498984761f)

typedef __attribute__((ext_vector_type(8))) short bf16x8;
typedef __attribute__((ext_vector_type(4))) float f32x4;
typedef unsigned short ushort_t;

__device__ inline unsigned pk_bf16(float a, float b) {
    __hip_bfloat162 h = __float22bfloat162_rn(make_float2(a, b));
    union { __hip_bfloat162 h2; unsigned u; } cv;
    cv.h2 = h;
    return cv.u;
}

__device__ inline bf16x8 pk8(float4 a, float4 b) {
    union { bf16x8 v; unsigned u[4]; } r;
    r.u[0] = pk_bf16(a.x, a.y);
    r.u[1] = pk_bf16(a.z, a.w);
    r.u[2] = pk_bf16(b.x, b.y);
    r.u[3] = pk_bf16(b.z, b.w);
    return r.v;
}

// async global->LDS, 16B per lane; lds base must be wave-uniform
__device__ inline void gld_lds16(const ushort_t* g, ushort_t* l) {
    __builtin_amdgcn_global_load_lds(
        (const __attribute__((address_space(1))) unsigned int*)g,
        (__attribute__((address_space(3))) unsigned int*)l,
        16, 0, 0);
}

// ---------------------------------------------------------------------------
// Swizzled-row bf16 cast of Q (x C1_SCALE) and K: row r (256 B = 16 atoms of
// 16 B), atom a stored at position a ^ (r & 15). Linear DMA of 16-row-aligned
// tiles reproduces the swizzled LDS image; fragment reads use atom
// ((c*4+quad) ^ ln) -> conflict-managed LDS banking.
// ---------------------------------------------------------------------------
__global__ __launch_bounds__(256) void cast_qk_sw(
    const float* __restrict__ Q, const float* __restrict__ K,
    ushort_t* __restrict__ Qb, ushort_t* __restrict__ Kb)
{
    const int g = blockIdx.x * 256 + threadIdx.x;   // atom id
    const int q = g >> 4, ap = g & 15;
    const int a = ap ^ (q & 15);
    const float* src = Q + (size_t)q * DK + a * 8;
    float4 x = *(const float4*)src, y = *(const float4*)(src + 4);
    x.x *= C1_SCALE; x.y *= C1_SCALE; x.z *= C1_SCALE; x.w *= C1_SCALE;
    y.x *= C1_SCALE; y.y *= C1_SCALE; y.z *= C1_SCALE; y.w *= C1_SCALE;
    *(bf16x8*)(Qb + (size_t)g * 8) = pk8(x, y);
    src = K + (size_t)q * DK + a * 8;
    float4 x2 = *(const float4*)src, y2 = *(const float4*)(src + 4);
    *(bf16x8*)(Kb + (size_t)g * 8) = pk8(x2, y2);
}

// ---------------------------------------------------------------------------
// Pass 1: l[b,k] partials = sum_q exp(s_qk).  = verified passA minus the P
// materialization.  Q tiles streamed global->LDS via global_load_lds (linear
// DMA, NO per-lane global gathers), double-buffered; K rows stationary in
// regs (gathered once).  grid (kt=32, qs=8, b=4), 256 thr, 16 KB LDS.
// ---------------------------------------------------------------------------
__global__ __launch_bounds__(256) void sdpa_lsum(
    const ushort_t* __restrict__ Qb, const ushort_t* __restrict__ Kb,
    float* __restrict__ lp)
{
    __shared__ ushort_t Qs[2][4096];   // 2 x (32 q x 128 dk), swizzled rows

    const int kt = blockIdx.x, qs = blockIdx.y, b = blockIdx.z;
    const int tid = threadIdx.x;
    const int w = tid >> 6, lane = tid & 63, ln = lane & 15, quad = lane >> 4;

    bf16x8 ka[2][4];   // A-frags: k rows kt*128 + w*32 + mt*16 + ln (swizzled)
#pragma unroll
    for (int mt = 0; mt < 2; ++mt)
#pragma unroll
        for (int c = 0; c < 4; ++c)
            ka[mt][c] = *(const bf16x8*)(Kb +
                ((size_t)(b * SEQ) + kt * 128 + w * 32 + mt * 16 + ln) * DK +
                (((c * 4 + quad) ^ ln) * 8));

    float ls[2][4] = {};
    const ushort_t* qtb = Qb + ((size_t)(b * SEQ + qs * 512)) * DK;

#define A_DMA(BUF, I)                                                          \
    {                                                                          \
        _Pragma("unroll")                                                      \
        for (int j = 0; j < 2; ++j)                                            \
            gld_lds16(qtb + (size_t)(I) * 4096 + (j * 256 + tid) * 8,          \
                      &Qs[BUF][(j * 256 + w * 64) * 8]);                       \
    }

#define A_CMP(BUF)                                                             \
    {                                                                          \
        bf16x8 qf[2][4];                                                       \
        _Pragma("unroll")                                                      \
        for (int nt = 0; nt < 2; ++nt)                                         \
            _Pragma("unroll")                                                  \
            for (int c = 0; c < 4; ++c)                                        \
                qf[nt][c] = *(const bf16x8*)&Qs[BUF][(nt * 16 + ln) * 128 +    \
                                    (((c * 4 + quad) ^ ln) * 8)];              \
        _Pragma("unroll")                                                      \
        for (int mt = 0; mt < 2; ++mt)                                         \
            _Pragma("unroll")                                                  \
            for (int nt = 0; nt < 2; ++nt) {                                   \
                f32x4 s = {0.f, 0.f, 0.f, 0.f};                                \
                __builtin_amdgcn_s_setprio(1);                                 \
                _Pragma("unroll")                                              \
                for (int c = 0; c < 4; ++c)                                    \
                    s = __builtin_amdgcn_mfma_f32_16x16x32_bf16(               \
                        ka[mt][c], qf[nt][c], s, 0, 0, 0);                     \
                __builtin_amdgcn_s_setprio(0);                                 \
                _Pragma("unroll")                                              \
                for (int r = 0; r < 4; ++r)                                    \
                    ls[mt][r] += __builtin_amdgcn_exp2f(s[r]);                 \
            }                                                                  \
    }

    A_DMA(0, 0)
    for (int ii = 0; ii < 8; ++ii) {
        const int i0 = 2 * ii;
        __syncthreads();              // Qs[0]=tile i0 ready
        A_DMA(1, i0 + 1)
        A_CMP(0)
        __syncthreads();              // Qs[1]=tile i0+1 ready; Qs[0] readers done
        if (ii < 7) A_DMA(0, i0 + 2)
        A_CMP(1)
    }
#undef A_DMA
#undef A_CMP

#pragma unroll
    for (int mt = 0; mt < 2; ++mt)
#pragma unroll
        for (int r = 0; r < 4; ++r) {
            float vv = ls[mt][r];
            vv += __shfl_xor(vv, 1);
            vv += __shfl_xor(vv, 2);
            vv += __shfl_xor(vv, 4);
            vv += __shfl_xor(vv, 8);
            ls[mt][r] = vv;
        }
    if (ln < 8) {
        int k = kt * 128 + w * 32 + (ln >> 2) * 16 + quad * 4 + (ln & 3);
        lp[((size_t)(qs * BS + b)) * SEQ + k] = ls[ln >> 2][ln & 3];
    }
}

// ---------------------------------------------------------------------------
// VbT[b][d][k] = bf16( V[b][k][d] / l[b][k] ), l = sum of 8 qs-partials.
// ---------------------------------------------------------------------------
__global__ __launch_bounds__(256) void vb_transpose(
    const float* __restrict__ V, const float* __restrict__ lp,
    ushort_t* __restrict__ VbT)
{
    __shared__ float Vl[64][132];
    __shared__ float Wl[64];

    const int kt = blockIdx.x, b = blockIdx.y;
    const int tid = threadIdx.x;
    const int k0 = kt * 64;
    {
        int r = tid >> 2, sg = tid & 3;
        const float* src = V + ((size_t)(b * SEQ) + k0 + r) * DK + sg * 32;
#pragma unroll
        for (int i = 0; i < 8; ++i)
            *(float4*)&Vl[r][sg * 32 + i * 4] = *(const float4*)(src + i * 4);
    }
    if (tid < 64) {
        float s = 0.f;
#pragma unroll
        for (int qs = 0; qs < 8; ++qs)
            s += lp[((size_t)(qs * BS + b)) * SEQ + k0 + tid];
        Wl[tid] = 1.0f / s;
    }
    __syncthreads();

    const int d = tid >> 1, kh = tid & 1;
    unsigned u[16];
#pragma unroll
    for (int j = 0; j < 16; ++j) {
        int row = kh * 32 + j * 2;
        u[j] = pk_bf16(Vl[row][d] * Wl[row], Vl[row + 1][d] * Wl[row + 1]);
    }
    ushort_t* dst = VbT + ((size_t)(b * DK) + d) * SEQ + k0 + kh * 32;
#pragma unroll
    for (int i = 0; i < 4; ++i) {
        uint4 t4; t4.x = u[i*4]; t4.y = u[i*4+1]; t4.z = u[i*4+2]; t4.w = u[i*4+3];
        *(uint4*)(dst + i * 8) = t4;
    }
}

// ---------------------------------------------------------------------------
// Pass 2: O_partial[ks] = exp(QK^T) . V'  — round-1 verified skeleton
// (waves split k for QK / split d for PV, P bounced through LDS, 2 barriers
// per 64-k phase), but ALL global gathers replaced by linear global_load_lds
// DMA of K and V tiles (double-buffered).  V tile is source-pre-swizzled
// (atom^(d&7)) so LDS B-frag reads are conflict-free; K tile rows carry the
// storage swizzle from cast_qk_sw.  72 KB LDS -> 2 blocks/CU.
// grid (x=16 (ks,b) [XCD-pinned], y=64 qt), 256 thr.
// ---------------------------------------------------------------------------
__global__ __launch_bounds__(256) void sdpa_out(
    const ushort_t* __restrict__ Qb, const ushort_t* __restrict__ Kb,
    const ushort_t* __restrict__ VbT,
    float* __restrict__ Op, float* __restrict__ O, int use_partial)
{
    __shared__ ushort_t Kt[2][8192];   // 64 k x 128 dk (swizzled rows, 256B)
    __shared__ ushort_t Vt[2][8192];   // 128 d x 64 k  (atom^(d&7), 128B rows)
    __shared__ ushort_t Pt[4096];      // 64 q x 64 k   (atom^(q&7))

    const int g  = blockIdx.x;
    const int qt = blockIdx.y;
    const int ks = g >> 2, b = g & 3;
    const int tid = threadIdx.x;
    const int w = tid >> 6, lane = tid & 63, ln = lane & 15, quad = lane >> 4;

    bf16x8 qa[4][4];   // Q tile qt*64..+64 stationary (B-operand frags)
#pragma unroll
    for (int nt = 0; nt < 4; ++nt)
#pragma unroll
        for (int c = 0; c < 4; ++c)
            qa[c][nt] = *(const bf16x8*)(Qb +
                ((size_t)(b * SEQ) + qt * 64 + nt * 16 + ln) * DK +
                (((c * 4 + quad) ^ ln) * 8));

    f32x4 acc[4][2];
#pragma unroll
    for (int i = 0; i < 4; ++i)
#pragma unroll
        for (int j = 0; j < 2; ++j) acc[i][j] = (f32x4){0.f, 0.f, 0.f, 0.f};

    const ushort_t* ksrc = Kb + ((size_t)(b * SEQ) + ks * 1024) * DK;
    const ushort_t* vsrc = VbT + ((size_t)(b * DK)) * SEQ + ks * 1024;
    const int vd = tid >> 3, vap = tid & 7;   // V-DMA thread coords

// stage K tile (16 KB contiguous) + V tile (16 KB, source pre-swizzled)
#define O_DMA(BUF, PH)                                                         \
    {                                                                          \
        _Pragma("unroll")                                                      \
        for (int j = 0; j < 4; ++j)                                            \
            gld_lds16(ksrc + (size_t)(PH) * 64 * DK + (j * 256 + tid) * 8,     \
                      &Kt[BUF][(j * 256 + w * 64) * 8]);                       \
        _Pragma("unroll")                                                      \
        for (int j = 0; j < 4; ++j)                                            \
            gld_lds16(vsrc + (size_t)(j * 32 + vd) * SEQ + (PH) * 64 +         \
                          ((vap ^ (vd & 7)) * 8),                              \
                      &Vt[BUF][(j * 256 + w * 64) * 8]);                       \
    }

// wave w computes P for its 16-k strip (rows w*16..+15 of the tile) x 64 q
#define QK_PHASE(BUF)                                                          \
    {                                                                          \
        bf16x8 kf[4];                                                          \
        _Pragma("unroll")                                                      \
        for (int c = 0; c < 4; ++c)                                            \
            kf[c] = *(const bf16x8*)&Kt[BUF][(w * 16 + ln) * 128 +             \
                                             (((c * 4 + quad) ^ ln) * 8)];     \
        _Pragma("unroll")                                                      \
        for (int nt = 0; nt < 4; ++nt) {                                       \
            f32x4 s = {0.f, 0.f, 0.f, 0.f};                                    \
            __builtin_amdgcn_s_setprio(1);                                     \
            _Pragma("unroll")                                                  \
            for (int c = 0; c < 4; ++c)                                        \
                s = __builtin_amdgcn_mfma_f32_16x16x32_bf16(kf[c], qa[c][nt], s, 0, 0, 0); \
            __builtin_amdgcn_s_setprio(0);                                     \
            uint2 pw;                                                          \
            pw.x = pk_bf16(__builtin_amdgcn_exp2f(s[0]),                       \
                           __builtin_amdgcn_exp2f(s[1]));                      \
            pw.y = pk_bf16(__builtin_amdgcn_exp2f(s[2]),                       \
                           __builtin_amdgcn_exp2f(s[3]));                      \
            const int q = nt * 16 + ln;                                        \
            const int a16 = w * 2 + (quad >> 1);                               \
            *(uint2*)&Pt[q * 64 + ((a16 ^ (q & 7)) * 8) + (quad & 1) * 4] = pw; \
        }                                                                      \
    }

// wave w consumes full 64k P x its 32-d strip of V
#define PV_PHASE(BUF)                                                          \
    {                                                                          \
        _Pragma("unroll")                                                      \
        for (int kc = 0; kc < 2; ++kc) {                                       \
            bf16x8 pa[4], vfr[2];                                              \
            _Pragma("unroll")                                                  \
            for (int qf2 = 0; qf2 < 4; ++qf2)                                  \
                pa[qf2] = *(const bf16x8*)&Pt[(qf2 * 16 + ln) * 64 +           \
                                    (((kc * 4 + quad) ^ (ln & 7)) * 8)];       \
            _Pragma("unroll")                                                  \
            for (int dt = 0; dt < 2; ++dt)                                     \
                vfr[dt] = *(const bf16x8*)&Vt[BUF][(w * 32 + dt * 16 + ln) * 64 + \
                                    (((kc * 4 + quad) ^ (ln & 7)) * 8)];       \
            __builtin_amdgcn_s_setprio(1);                                     \
            _Pragma("unroll")                                                  \
            for (int qf2 = 0; qf2 < 4; ++qf2)                                  \
                _Pragma("unroll")                                              \
                for (int dt = 0; dt < 2; ++dt)                                 \
                    acc[qf2][dt] = __builtin_amdgcn_mfma_f32_16x16x32_bf16(    \
                        pa[qf2], vfr[dt], acc[qf2][dt], 0, 0, 0);              \
            __builtin_amdgcn_s_setprio(0);                                     \
        }                                                                      \
    }

    O_DMA(0, 0)
    for (int ph = 0; ph < 16; ++ph) {
        const int cur = ph & 1;
        __syncthreads();              // K/V buf[cur] DMA complete; Pt free
        if (ph < 15) O_DMA(cur ^ 1, ph + 1)
        QK_PHASE(cur)
        __syncthreads();              // Pt complete
        PV_PHASE(cur)
    }
#undef O_DMA
#undef QK_PHASE
#undef PV_PHASE

    if (use_partial) {
        float* dst = Op + (size_t)ks * ((size_t)BS * SEQ * DK) +
                     ((size_t)(b * SEQ) + qt * 64 + quad * 4) * DK + w * 32 + ln;
#pragma unroll
        for (int qf2 = 0; qf2 < 4; ++qf2)
#pragma unroll
            for (int dt = 0; dt < 2; ++dt)
#pragma unroll
                for (int r = 0; r < 4; ++r)
                    dst[((size_t)(qf2 * 16 + r)) * DK + dt * 16] = acc[qf2][dt][r];
    } else {
#pragma unroll
        for (int qf2 = 0; qf2 < 4; ++qf2)
#pragma unroll
            for (int dt = 0; dt < 2; ++dt)
#pragma unroll
                for (int r = 0; r < 4; ++r)
                    atomicAdd(&O[((size_t)(b * SEQ) + qt * 64 + qf2 * 16 + quad * 4 + r) * DK +
                                 w * 32 + dt * 16 + ln], acc[qf2][dt][r]);
    }
}

// ---------------------------------------------------------------------------
// reduce4: O = sum of 4 k-split partials (float4 per thread).
// ---------------------------------------------------------------------------
__global__ __launch_bounds__(256) void reduce4(
    const float* __restrict__ Op, float* __restrict__ O)
{
    const size_t N = (size_t)BS * SEQ * DK;
    size_t i = ((size_t)blockIdx.x * 256 + threadIdx.x) * 4;
    float4 a0 = *(const float4*)(Op + i);
    float4 a1 = *(const float4*)(Op + N + i);
    float4 a2 = *(const float4*)(Op + 2 * N + i);
    float4 a3 = *(const float4*)(Op + 3 * N + i);
    float4 r;
    r.x = a0.x + a1.x + a2.x + a3.x;
    r.y = a0.y + a1.y + a2.y + a3.y;
    r.z = a0.z + a1.z + a2.z + a3.z;
    r.w = a0.w + a1.w + a2.w + a3.w;
    *(float4*)(O + i) = r;
}

extern "C" void kernel_launch(void* const* d_in, const int* in_sizes, int n_in,
                              void* d_out, int out_size, void* d_ws, size_t ws_size,
                              hipStream_t stream) {
    const float* q = (const float*)d_in[0];
    const float* k = (const float*)d_in[1];
    const float* v = (const float*)d_in[2];
    float* out = (float*)d_out;

    const size_t QKV = (size_t)BS * SEQ * DK;           // 2 M elements
    float*    lp  = (float*)d_ws;                       // 512 KB used
    ushort_t* Qb  = (ushort_t*)((char*)d_ws + (1 << 20));
    ushort_t* Kb  = Qb + QKV;
    ushort_t* VbT = Kb + QKV;
    float*    Op  = (float*)(VbT + QKV);                // 33.6 MB (4 k-splits)

    const size_t need_p = (1u << 20) + 3 * QKV * 2 + 4 * QKV * sizeof(float);

    cast_qk_sw<<<dim3(BS * SEQ * 16 / 256), 256, 0, stream>>>(q, k, Qb, Kb);
    sdpa_lsum  <<<dim3(32, 8, 4), 256, 0, stream>>>(Qb, Kb, lp);
    vb_transpose<<<dim3(64, 4),   256, 0, stream>>>(v, lp, VbT);

    if (ws_size >= need_p) {
        sdpa_out<<<dim3(16, 64), 256, 0, stream>>>(Qb, Kb, VbT, Op, out, 1);
        reduce4 <<<dim3(BS * SEQ * DK / 4 / 256), 256, 0, stream>>>(Op, out);
    } else {
        hipMemsetAsync(out, 0, QKV * sizeof(float), stream);
        sdpa_out<<<dim3(16, 64), 256, 0, stream>>>(Qb, Kb, VbT, nullptr, out, 0);
    }
}

// Round 4
// 153.058 us; speedup vs baseline: 1.7409x; 1.1265x over previous
//
#include <hip/hip_runtime.h>
#include <hip/hip_bf16.h>

#define BS  4
#define SEQ 4096
#define DK  128

// p = exp(s_raw / sqrt(128)) = exp2(C1_SCALE * s_raw).  C1_SCALE is folded
// into the bf16 cast of Q (replaces the cast rounding, does not add one), so
// the MFMA output is already in log2 domain: p = exp2(s).
#define C1_SCALE (1.4426950408889634f / 11.313708498984761f)

typedef __attribute__((ext_vector_type(8))) short bf16x8;
typedef __attribute__((ext_vector_type(4))) float f32x4;
typedef unsigned short ushort_t;

__device__ inline unsigned pk_bf16(float a, float b) {
    __hip_bfloat162 h = __float22bfloat162_rn(make_float2(a, b));
    union { __hip_bfloat162 h2; unsigned u; } cv;
    cv.h2 = h;
    return cv.u;
}

__device__ inline bf16x8 pk8(float4 a, float4 b) {
    union { bf16x8 v; unsigned u[4]; } r;
    r.u[0] = pk_bf16(a.x, a.y);
    r.u[1] = pk_bf16(a.z, a.w);
    r.u[2] = pk_bf16(b.x, b.y);
    r.u[3] = pk_bf16(b.z, b.w);
    return r.v;
}

// async global->LDS, 16B per lane; lds base must be wave-uniform
__device__ inline void gld_lds16(const ushort_t* g, ushort_t* l) {
    __builtin_amdgcn_global_load_lds(
        (const __attribute__((address_space(1))) unsigned int*)g,
        (__attribute__((address_space(3))) unsigned int*)l,
        16, 0, 0);
}

// raw barrier + compiler memory fence on the exit side (keeps LDS ops from
// being hoisted above / sunk below the barrier; the entry side is always
// pinned by the memory-clobber s_waitcnt asm directly before it)
__device__ inline void bar_fence() {
    __builtin_amdgcn_s_barrier();
    asm volatile("" ::: "memory");
}

// ---------------------------------------------------------------------------
// Swizzled-row bf16 cast of Q (x C1_SCALE) and K: row r (256 B = 16 atoms of
// 16 B), atom a stored at position a ^ (r & 15). Linear DMA of 16-row-aligned
// tiles reproduces the swizzled LDS image; fragment reads use atom
// ((c*4+quad) ^ ln) -> conflict-managed LDS banking.
// ---------------------------------------------------------------------------
__global__ __launch_bounds__(256) void cast_qk_sw(
    const float* __restrict__ Q, const float* __restrict__ K,
    ushort_t* __restrict__ Qb, ushort_t* __restrict__ Kb)
{
    const int g = blockIdx.x * 256 + threadIdx.x;   // atom id
    const int q = g >> 4, ap = g & 15;
    const int a = ap ^ (q & 15);
    const float* src = Q + (size_t)q * DK + a * 8;
    float4 x = *(const float4*)src, y = *(const float4*)(src + 4);
    x.x *= C1_SCALE; x.y *= C1_SCALE; x.z *= C1_SCALE; x.w *= C1_SCALE;
    y.x *= C1_SCALE; y.y *= C1_SCALE; y.z *= C1_SCALE; y.w *= C1_SCALE;
    *(bf16x8*)(Qb + (size_t)g * 8) = pk8(x, y);
    src = K + (size_t)q * DK + a * 8;
    float4 x2 = *(const float4*)src, y2 = *(const float4*)(src + 4);
    *(bf16x8*)(Kb + (size_t)g * 8) = pk8(x2, y2);
}

// ---------------------------------------------------------------------------
// Pass 1: l[b,k] partials = sum_q exp(s_qk).  Triple-buffered Q tiles via
// global_load_lds with COUNTED vmcnt (never 0 in-loop): DMA(t+2) issued at
// tile t into the buffer retired at t-1; one barrier per tile; each DMA has
// a two-tile in-flight window.  grid (kt=32, qs=8, b=4), 256 thr, 24 KB LDS.
// ---------------------------------------------------------------------------
__global__ __launch_bounds__(256) void sdpa_lsum(
    const ushort_t* __restrict__ Qb, const ushort_t* __restrict__ Kb,
    float* __restrict__ lp)
{
    __shared__ ushort_t Qs[3][4096];   // 3 x (32 q x 128 dk), swizzled rows

    const int kt = blockIdx.x, qs = blockIdx.y, b = blockIdx.z;
    const int tid = threadIdx.x;
    const int w = tid >> 6, lane = tid & 63, ln = lane & 15, quad = lane >> 4;

    bf16x8 ka[2][4];   // A-frags: k rows kt*128 + w*32 + mt*16 + ln (swizzled)
#pragma unroll
    for (int mt = 0; mt < 2; ++mt)
#pragma unroll
        for (int c = 0; c < 4; ++c)
            ka[mt][c] = *(const bf16x8*)(Kb +
                ((size_t)(b * SEQ) + kt * 128 + w * 32 + mt * 16 + ln) * DK +
                (((c * 4 + quad) ^ ln) * 8));

    float ls[2][4] = {};
    const ushort_t* qtb = Qb + ((size_t)(b * SEQ + qs * 512)) * DK;

#define A_DMA(BUF, I)                                                          \
    {                                                                          \
        _Pragma("unroll")                                                      \
        for (int j = 0; j < 2; ++j)                                            \
            gld_lds16(qtb + (size_t)(I) * 4096 + (j * 256 + tid) * 8,          \
                      &Qs[BUF][(j * 256 + w * 64) * 8]);                       \
    }

#define A_CMP(BUF)                                                             \
    {                                                                          \
        bf16x8 qf[2][4];                                                       \
        _Pragma("unroll")                                                      \
        for (int nt = 0; nt < 2; ++nt)                                         \
            _Pragma("unroll")                                                  \
            for (int c = 0; c < 4; ++c)                                        \
                qf[nt][c] = *(const bf16x8*)&Qs[BUF][(nt * 16 + ln) * 128 +    \
                                    (((c * 4 + quad) ^ ln) * 8)];              \
        _Pragma("unroll")                                                      \
        for (int mt = 0; mt < 2; ++mt)                                         \
            _Pragma("unroll")                                                  \
            for (int nt = 0; nt < 2; ++nt) {                                   \
                f32x4 s = {0.f, 0.f, 0.f, 0.f};                                \
                __builtin_amdgcn_s_setprio(1);                                 \
                _Pragma("unroll")                                              \
                for (int c = 0; c < 4; ++c)                                    \
                    s = __builtin_amdgcn_mfma_f32_16x16x32_bf16(               \
                        ka[mt][c], qf[nt][c], s, 0, 0, 0);                     \
                __builtin_amdgcn_s_setprio(0);                                 \
                _Pragma("unroll")                                              \
                for (int r = 0; r < 4; ++r)                                    \
                    ls[mt][r] += __builtin_amdgcn_exp2f(s[r]);                 \
            }                                                                  \
    }

    A_DMA(0, 0)
    A_DMA(1, 1)
    for (int t = 0; t < 15; ++t) {
        // DMA(t) done (DMA(t+1)'s 2 loads stay in flight); tile t-1 readers done
        asm volatile("s_waitcnt vmcnt(2) lgkmcnt(0)" ::: "memory");
        bar_fence();
        if (t < 14) A_DMA((t + 2) % 3, t + 2)   // buffer retired at tile t-1
        A_CMP(t % 3)
    }
    asm volatile("s_waitcnt vmcnt(0) lgkmcnt(0)" ::: "memory");
    bar_fence();
    A_CMP(0)                                    // tile 15 -> buf 15%3 == 0
#undef A_DMA
#undef A_CMP

#pragma unroll
    for (int mt = 0; mt < 2; ++mt)
#pragma unroll
        for (int r = 0; r < 4; ++r) {
            float vv = ls[mt][r];
            vv += __shfl_xor(vv, 1);
            vv += __shfl_xor(vv, 2);
            vv += __shfl_xor(vv, 4);
            vv += __shfl_xor(vv, 8);
            ls[mt][r] = vv;
        }
    if (ln < 8) {
        int k = kt * 128 + w * 32 + (ln >> 2) * 16 + quad * 4 + (ln & 3);
        lp[((size_t)(qs * BS + b)) * SEQ + k] = ls[ln >> 2][ln & 3];
    }
}

// ---------------------------------------------------------------------------
// VbT[b][d][k] = bf16( V[b][k][d] / l[b][k] ), l = sum of 8 qs-partials.
// ---------------------------------------------------------------------------
__global__ __launch_bounds__(256) void vb_transpose(
    const float* __restrict__ V, const float* __restrict__ lp,
    ushort_t* __restrict__ VbT)
{
    __shared__ float Vl[64][132];
    __shared__ float Wl[64];

    const int kt = blockIdx.x, b = blockIdx.y;
    const int tid = threadIdx.x;
    const int k0 = kt * 64;
    {
        int r = tid >> 2, sg = tid & 3;
        const float* src = V + ((size_t)(b * SEQ) + k0 + r) * DK + sg * 32;
#pragma unroll
        for (int i = 0; i < 8; ++i)
            *(float4*)&Vl[r][sg * 32 + i * 4] = *(const float4*)(src + i * 4);
    }
    if (tid < 64) {
        float s = 0.f;
#pragma unroll
        for (int qs = 0; qs < 8; ++qs)
            s += lp[((size_t)(qs * BS + b)) * SEQ + k0 + tid];
        Wl[tid] = 1.0f / s;
    }
    __syncthreads();

    const int d = tid >> 1, kh = tid & 1;
    unsigned u[16];
#pragma unroll
    for (int j = 0; j < 16; ++j) {
        int row = kh * 32 + j * 2;
        u[j] = pk_bf16(Vl[row][d] * Wl[row], Vl[row + 1][d] * Wl[row + 1]);
    }
    ushort_t* dst = VbT + ((size_t)(b * DK) + d) * SEQ + k0 + kh * 32;
#pragma unroll
    for (int i = 0; i < 4; ++i) {
        uint4 t4; t4.x = u[i*4]; t4.y = u[i*4+1]; t4.z = u[i*4+2]; t4.w = u[i*4+3];
        *(uint4*)(dst + i * 8) = t4;
    }
}

// ---------------------------------------------------------------------------
// Pass 2: O_partial[ks] = exp(QK^T) . V'  — same fragment math as round-3
// (waves split k for QK / split d for PV, P bounced through LDS), but the
// sync structure is converted to COUNTED vmcnt + raw barriers (T4):
//   prologue: stage phases 0 and 1 (16 loads in flight)
//   per phase: vmcnt(8)+bar  (buf[cur] ready; next phase's 8 loads IN FLIGHT
//              across the barrier) -> QK -> lgkm(0)+bar (Pt ready, NO vmcnt
//              drain) -> PV -> lgkm(0)+bar (readers done) -> stage phase+2.
// Each DMA gets a full-phase in-flight window; vmcnt never drains to 0 in
// the main loop (final phase peeled).
// grid (x=16 (ks,b) [XCD-pinned], y=64 qt), 256 thr, 72 KB LDS.
// ---------------------------------------------------------------------------
__global__ __launch_bounds__(256) void sdpa_out(
    const ushort_t* __restrict__ Qb, const ushort_t* __restrict__ Kb,
    const ushort_t* __restrict__ VbT,
    float* __restrict__ Op, float* __restrict__ O, int use_partial)
{
    __shared__ ushort_t Kt[2][8192];   // 64 k x 128 dk (swizzled rows, 256B)
    __shared__ ushort_t Vt[2][8192];   // 128 d x 64 k  (atom^(d&7), 128B rows)
    __shared__ ushort_t Pt[4096];      // 64 q x 64 k   (atom^(q&7))

    const int g  = blockIdx.x;
    const int qt = blockIdx.y;
    const int ks = g >> 2, b = g & 3;
    const int tid = threadIdx.x;
    const int w = tid >> 6, lane = tid & 63, ln = lane & 15, quad = lane >> 4;

    bf16x8 qa[4][4];   // Q tile qt*64..+64 stationary (B-operand frags)
#pragma unroll
    for (int nt = 0; nt < 4; ++nt)
#pragma unroll
        for (int c = 0; c < 4; ++c)
            qa[c][nt] = *(const bf16x8*)(Qb +
                ((size_t)(b * SEQ) + qt * 64 + nt * 16 + ln) * DK +
                (((c * 4 + quad) ^ ln) * 8));

    f32x4 acc[4][2];
#pragma unroll
    for (int i = 0; i < 4; ++i)
#pragma unroll
        for (int j = 0; j < 2; ++j) acc[i][j] = (f32x4){0.f, 0.f, 0.f, 0.f};

    const ushort_t* ksrc = Kb + ((size_t)(b * SEQ) + ks * 1024) * DK;
    const ushort_t* vsrc = VbT + ((size_t)(b * DK)) * SEQ + ks * 1024;
    const int vd = tid >> 3, vap = tid & 7;   // V-DMA thread coords

// stage K tile (16 KB contiguous) + V tile (16 KB, source pre-swizzled)
#define O_DMA(BUF, PH)                                                         \
    {                                                                          \
        _Pragma("unroll")                                                      \
        for (int j = 0; j < 4; ++j)                                            \
            gld_lds16(ksrc + (size_t)(PH) * 64 * DK + (j * 256 + tid) * 8,     \
                      &Kt[BUF][(j * 256 + w * 64) * 8]);                       \
        _Pragma("unroll")                                                      \
        for (int j = 0; j < 4; ++j)                                            \
            gld_lds16(vsrc + (size_t)(j * 32 + vd) * SEQ + (PH) * 64 +         \
                          ((vap ^ (vd & 7)) * 8),                              \
                      &Vt[BUF][(j * 256 + w * 64) * 8]);                       \
    }

// wave w computes P for its 16-k strip (rows w*16..+15 of the tile) x 64 q
#define QK_PHASE(BUF)                                                          \
    {                                                                          \
        bf16x8 kf[4];                                                          \
        _Pragma("unroll")                                                      \
        for (int c = 0; c < 4; ++c)                                            \
            kf[c] = *(const bf16x8*)&Kt[BUF][(w * 16 + ln) * 128 +             \
                                             (((c * 4 + quad) ^ ln) * 8)];     \
        _Pragma("unroll")                                                      \
        for (int nt = 0; nt < 4; ++nt) {                                       \
            f32x4 s = {0.f, 0.f, 0.f, 0.f};                                    \
            __builtin_amdgcn_s_setprio(1);                                     \
            _Pragma("unroll")                                                  \
            for (int c = 0; c < 4; ++c)                                        \
                s = __builtin_amdgcn_mfma_f32_16x16x32_bf16(kf[c], qa[c][nt], s, 0, 0, 0); \
            __builtin_amdgcn_s_setprio(0);                                     \
            uint2 pw;                                                          \
            pw.x = pk_bf16(__builtin_amdgcn_exp2f(s[0]),                       \
                           __builtin_amdgcn_exp2f(s[1]));                      \
            pw.y = pk_bf16(__builtin_amdgcn_exp2f(s[2]),                       \
                           __builtin_amdgcn_exp2f(s[3]));                      \
            const int q = nt * 16 + ln;                                        \
            const int a16 = w * 2 + (quad >> 1);                               \
            *(uint2*)&Pt[q * 64 + ((a16 ^ (q & 7)) * 8) + (quad & 1) * 4] = pw; \
        }                                                                      \
    }

// wave w consumes full 64k P x its 32-d strip of V
#define PV_PHASE(BUF)                                                          \
    {                                                                          \
        _Pragma("unroll")                                                      \
        for (int kc = 0; kc < 2; ++kc) {                                       \
            bf16x8 pa[4], vfr[2];                                              \
            _Pragma("unroll")                                                  \
            for (int qf2 = 0; qf2 < 4; ++qf2)                                  \
                pa[qf2] = *(const bf16x8*)&Pt[(qf2 * 16 + ln) * 64 +           \
                                    (((kc * 4 + quad) ^ (ln & 7)) * 8)];       \
            _Pragma("unroll")                                                  \
            for (int dt = 0; dt < 2; ++dt)                                     \
                vfr[dt] = *(const bf16x8*)&Vt[BUF][(w * 32 + dt * 16 + ln) * 64 + \
                                    (((kc * 4 + quad) ^ (ln & 7)) * 8)];       \
            __builtin_amdgcn_s_setprio(1);                                     \
            _Pragma("unroll")                                                  \
            for (int qf2 = 0; qf2 < 4; ++qf2)                                  \
                _Pragma("unroll")                                              \
                for (int dt = 0; dt < 2; ++dt)                                 \
                    acc[qf2][dt] = __builtin_amdgcn_mfma_f32_16x16x32_bf16(    \
                        pa[qf2], vfr[dt], acc[qf2][dt], 0, 0, 0);              \
            __builtin_amdgcn_s_setprio(0);                                     \
        }                                                                      \
    }

    O_DMA(0, 0)
    O_DMA(1, 1)
    for (int ph = 0; ph < 15; ++ph) {
        const int cur = ph & 1;
        // DMA(ph) complete; DMA(ph+1)'s 8 loads remain in flight across barrier
        asm volatile("s_waitcnt vmcnt(8)" ::: "memory");
        bar_fence();                   // buf[cur] ready everywhere
        QK_PHASE(cur)
        asm volatile("s_waitcnt lgkmcnt(0)" ::: "memory");
        bar_fence();                   // Pt ready (no vmcnt drain!)
        PV_PHASE(cur)
        asm volatile("s_waitcnt lgkmcnt(0)" ::: "memory");
        bar_fence();                   // all waves done reading buf[cur]
        if (ph < 14) O_DMA(cur, ph + 2)
    }
    // peeled final phase (ph = 15, cur = 1): only its own 8 loads outstanding
    asm volatile("s_waitcnt vmcnt(0)" ::: "memory");
    bar_fence();
    QK_PHASE(1)
    asm volatile("s_waitcnt lgkmcnt(0)" ::: "memory");
    bar_fence();
    PV_PHASE(1)
#undef O_DMA
#undef QK_PHASE
#undef PV_PHASE

    if (use_partial) {
        float* dst = Op + (size_t)ks * ((size_t)BS * SEQ * DK) +
                     ((size_t)(b * SEQ) + qt * 64 + quad * 4) * DK + w * 32 + ln;
#pragma unroll
        for (int qf2 = 0; qf2 < 4; ++qf2)
#pragma unroll
            for (int dt = 0; dt < 2; ++dt)
#pragma unroll
                for (int r = 0; r < 4; ++r)
                    dst[((size_t)(qf2 * 16 + r)) * DK + dt * 16] = acc[qf2][dt][r];
    } else {
#pragma unroll
        for (int qf2 = 0; qf2 < 4; ++qf2)
#pragma unroll
            for (int dt = 0; dt < 2; ++dt)
#pragma unroll
                for (int r = 0; r < 4; ++r)
                    atomicAdd(&O[((size_t)(b * SEQ) + qt * 64 + qf2 * 16 + quad * 4 + r) * DK +
                                 w * 32 + dt * 16 + ln], acc[qf2][dt][r]);
    }
}

// ---------------------------------------------------------------------------
// reduce4: O = sum of 4 k-split partials (float4 per thread).
// ---------------------------------------------------------------------------
__global__ __launch_bounds__(256) void reduce4(
    const float* __restrict__ Op, float* __restrict__ O)
{
    const size_t N = (size_t)BS * SEQ * DK;
    size_t i = ((size_t)blockIdx.x * 256 + threadIdx.x) * 4;
    float4 a0 = *(const float4*)(Op + i);
    float4 a1 = *(const float4*)(Op + N + i);
    float4 a2 = *(const float4*)(Op + 2 * N + i);
    float4 a3 = *(const float4*)(Op + 3 * N + i);
    float4 r;
    r.x = a0.x + a1.x + a2.x + a3.x;
    r.y = a0.y + a1.y + a2.y + a3.y;
    r.z = a0.z + a1.z + a2.z + a3.z;
    r.w = a0.w + a1.w + a2.w + a3.w;
    *(float4*)(O + i) = r;
}

extern "C" void kernel_launch(void* const* d_in, const int* in_sizes, int n_in,
                              void* d_out, int out_size, void* d_ws, size_t ws_size,
                              hipStream_t stream) {
    const float* q = (const float*)d_in[0];
    const float* k = (const float*)d_in[1];
    const float* v = (const float*)d_in[2];
    float* out = (float*)d_out;

    const size_t QKV = (size_t)BS * SEQ * DK;           // 2 M elements
    float*    lp  = (float*)d_ws;                       // 512 KB used
    ushort_t* Qb  = (ushort_t*)((char*)d_ws + (1 << 20));
    ushort_t* Kb  = Qb + QKV;
    ushort_t* VbT = Kb + QKV;
    float*    Op  = (float*)(VbT + QKV);                // 33.6 MB (4 k-splits)

    const size_t need_p = (1u << 20) + 3 * QKV * 2 + 4 * QKV * sizeof(float);

    cast_qk_sw<<<dim3(BS * SEQ * 16 / 256), 256, 0, stream>>>(q, k, Qb, Kb);
    sdpa_lsum  <<<dim3(32, 8, 4), 256, 0, stream>>>(Qb, Kb, lp);
    vb_transpose<<<dim3(64, 4),   256, 0, stream>>>(v, lp, VbT);

    if (ws_size >= need_p) {
        sdpa_out<<<dim3(16, 64), 256, 0, stream>>>(Qb, Kb, VbT, Op, out, 1);
        reduce4 <<<dim3(BS * SEQ * DK / 4 / 256), 256, 0, stream>>>(Op, out);
    } else {
        hipMemsetAsync(out, 0, QKV * sizeof(float), stream);
        sdpa_out<<<dim3(16, 64), 256, 0, stream>>>(Qb, Kb, VbT, nullptr, out, 0);
    }
}

// Round 5
// 147.714 us; speedup vs baseline: 1.8039x; 1.0362x over previous
//
#include <hip/hip_runtime.h>
#include <hip/hip_bf16.h>

#define BS  4
#define SEQ 4096
#define DK  128

// p = exp(s_raw / sqrt(128)) = exp2(C1_SCALE * s_raw).  C1_SCALE is folded
// into the bf16 cast of Q (replaces the cast rounding, does not add one), so
// the MFMA output is already in log2 domain: p = exp2(s).
#define C1_SCALE (1.4426950408889634f / 11.313708498984761f)

typedef __attribute__((ext_vector_type(8))) short bf16x8;
typedef __attribute__((ext_vector_type(4))) float f32x4;
typedef unsigned short ushort_t;

__device__ inline unsigned pk_bf16(float a, float b) {
    __hip_bfloat162 h = __float22bfloat162_rn(make_float2(a, b));
    union { __hip_bfloat162 h2; unsigned u; } cv;
    cv.h2 = h;
    return cv.u;
}

__device__ inline bf16x8 pk8(float4 a, float4 b) {
    union { bf16x8 v; unsigned u[4]; } r;
    r.u[0] = pk_bf16(a.x, a.y);
    r.u[1] = pk_bf16(a.z, a.w);
    r.u[2] = pk_bf16(b.x, b.y);
    r.u[3] = pk_bf16(b.z, b.w);
    return r.v;
}

// async global->LDS, 16B per lane; lds base must be wave-uniform
__device__ inline void gld_lds16(const ushort_t* g, ushort_t* l) {
    __builtin_amdgcn_global_load_lds(
        (const __attribute__((address_space(1))) unsigned int*)g,
        (__attribute__((address_space(3))) unsigned int*)l,
        16, 0, 0);
}

__device__ inline void bar_fence() {
    __builtin_amdgcn_s_barrier();
    asm volatile("" ::: "memory");
}

// ---------------------------------------------------------------------------
// Swizzled-row bf16 cast of Q (x C1_SCALE) and K: row r (256 B = 16 atoms of
// 16 B), atom a stored at position a ^ (r & 15). Linear DMA of 16-row-aligned
// tiles reproduces the swizzled LDS image; fragment reads use atom
// ((c*4+quad) ^ ln) -> conflict-managed LDS banking.
// ---------------------------------------------------------------------------
__global__ __launch_bounds__(256) void cast_qk_sw(
    const float* __restrict__ Q, const float* __restrict__ K,
    ushort_t* __restrict__ Qb, ushort_t* __restrict__ Kb)
{
    const int g = blockIdx.x * 256 + threadIdx.x;   // atom id
    const int q = g >> 4, ap = g & 15;
    const int a = ap ^ (q & 15);
    const float* src = Q + (size_t)q * DK + a * 8;
    float4 x = *(const float4*)src, y = *(const float4*)(src + 4);
    x.x *= C1_SCALE; x.y *= C1_SCALE; x.z *= C1_SCALE; x.w *= C1_SCALE;
    y.x *= C1_SCALE; y.y *= C1_SCALE; y.z *= C1_SCALE; y.w *= C1_SCALE;
    *(bf16x8*)(Qb + (size_t)g * 8) = pk8(x, y);
    src = K + (size_t)q * DK + a * 8;
    float4 x2 = *(const float4*)src, y2 = *(const float4*)(src + 4);
    *(bf16x8*)(Kb + (size_t)g * 8) = pk8(x2, y2);
}

// ---------------------------------------------------------------------------
// Pass 1: l[b,k] partials = sum_q exp(s_qk).  Triple-buffered Q tiles via
// global_load_lds with COUNTED vmcnt (never 0 in-loop).  Unchanged from the
// round-4 version (it improved).
// ---------------------------------------------------------------------------
__global__ __launch_bounds__(256) void sdpa_lsum(
    const ushort_t* __restrict__ Qb, const ushort_t* __restrict__ Kb,
    float* __restrict__ lp)
{
    __shared__ ushort_t Qs[3][4096];   // 3 x (32 q x 128 dk), swizzled rows

    const int kt = blockIdx.x, qs = blockIdx.y, b = blockIdx.z;
    const int tid = threadIdx.x;
    const int w = tid >> 6, lane = tid & 63, ln = lane & 15, quad = lane >> 4;

    bf16x8 ka[2][4];
#pragma unroll
    for (int mt = 0; mt < 2; ++mt)
#pragma unroll
        for (int c = 0; c < 4; ++c)
            ka[mt][c] = *(const bf16x8*)(Kb +
                ((size_t)(b * SEQ) + kt * 128 + w * 32 + mt * 16 + ln) * DK +
                (((c * 4 + quad) ^ ln) * 8));

    float ls[2][4] = {};
    const ushort_t* qtb = Qb + ((size_t)(b * SEQ + qs * 512)) * DK;

#define A_DMA(BUF, I)                                                          \
    {                                                                          \
        _Pragma("unroll")                                                      \
        for (int j = 0; j < 2; ++j)                                            \
            gld_lds16(qtb + (size_t)(I) * 4096 + (j * 256 + tid) * 8,          \
                      &Qs[BUF][(j * 256 + w * 64) * 8]);                       \
    }

#define A_CMP(BUF)                                                             \
    {                                                                          \
        bf16x8 qf[2][4];                                                       \
        _Pragma("unroll")                                                      \
        for (int nt = 0; nt < 2; ++nt)                                         \
            _Pragma("unroll")                                                  \
            for (int c = 0; c < 4; ++c)                                        \
                qf[nt][c] = *(const bf16x8*)&Qs[BUF][(nt * 16 + ln) * 128 +    \
                                    (((c * 4 + quad) ^ ln) * 8)];              \
        _Pragma("unroll")                                                      \
        for (int mt = 0; mt < 2; ++mt)                                         \
            _Pragma("unroll")                                                  \
            for (int nt = 0; nt < 2; ++nt) {                                   \
                f32x4 s = {0.f, 0.f, 0.f, 0.f};                                \
                __builtin_amdgcn_s_setprio(1);                                 \
                _Pragma("unroll")                                              \
                for (int c = 0; c < 4; ++c)                                    \
                    s = __builtin_amdgcn_mfma_f32_16x16x32_bf16(               \
                        ka[mt][c], qf[nt][c], s, 0, 0, 0);                     \
                __builtin_amdgcn_s_setprio(0);                                 \
                _Pragma("unroll")                                              \
                for (int r = 0; r < 4; ++r)                                    \
                    ls[mt][r] += __builtin_amdgcn_exp2f(s[r]);                 \
            }                                                                  \
    }

    A_DMA(0, 0)
    A_DMA(1, 1)
    for (int t = 0; t < 15; ++t) {
        asm volatile("s_waitcnt vmcnt(2) lgkmcnt(0)" ::: "memory");
        bar_fence();
        if (t < 14) A_DMA((t + 2) % 3, t + 2)
        A_CMP(t % 3)
    }
    asm volatile("s_waitcnt vmcnt(0) lgkmcnt(0)" ::: "memory");
    bar_fence();
    A_CMP(0)
#undef A_DMA
#undef A_CMP

#pragma unroll
    for (int mt = 0; mt < 2; ++mt)
#pragma unroll
        for (int r = 0; r < 4; ++r) {
            float vv = ls[mt][r];
            vv += __shfl_xor(vv, 1);
            vv += __shfl_xor(vv, 2);
            vv += __shfl_xor(vv, 4);
            vv += __shfl_xor(vv, 8);
            ls[mt][r] = vv;
        }
    if (ln < 8) {
        int k = kt * 128 + w * 32 + (ln >> 2) * 16 + quad * 4 + (ln & 3);
        lp[((size_t)(qs * BS + b)) * SEQ + k] = ls[ln >> 2][ln & 3];
    }
}

// ---------------------------------------------------------------------------
// VbT[b][d][k] = bf16( V[b][k][d] / l[b][k] ), l = sum of 8 qs-partials.
// ---------------------------------------------------------------------------
__global__ __launch_bounds__(256) void vb_transpose(
    const float* __restrict__ V, const float* __restrict__ lp,
    ushort_t* __restrict__ VbT)
{
    __shared__ float Vl[64][132];
    __shared__ float Wl[64];

    const int kt = blockIdx.x, b = blockIdx.y;
    const int tid = threadIdx.x;
    const int k0 = kt * 64;
    {
        int r = tid >> 2, sg = tid & 3;
        const float* src = V + ((size_t)(b * SEQ) + k0 + r) * DK + sg * 32;
#pragma unroll
        for (int i = 0; i < 8; ++i)
            *(float4*)&Vl[r][sg * 32 + i * 4] = *(const float4*)(src + i * 4);
    }
    if (tid < 64) {
        float s = 0.f;
#pragma unroll
        for (int qs = 0; qs < 8; ++qs)
            s += lp[((size_t)(qs * BS + b)) * SEQ + k0 + tid];
        Wl[tid] = 1.0f / s;
    }
    __syncthreads();

    const int d = tid >> 1, kh = tid & 1;
    unsigned u[16];
#pragma unroll
    for (int j = 0; j < 16; ++j) {
        int row = kh * 32 + j * 2;
        u[j] = pk_bf16(Vl[row][d] * Wl[row], Vl[row + 1][d] * Wl[row + 1]);
    }
    ushort_t* dst = VbT + ((size_t)(b * DK) + d) * SEQ + k0 + kh * 32;
#pragma unroll
    for (int i = 0; i < 4; ++i) {
        uint4 t4; t4.x = u[i*4]; t4.y = u[i*4+1]; t4.z = u[i*4+2]; t4.w = u[i*4+3];
        *(uint4*)(dst + i * 8) = t4;
    }
}

// ---------------------------------------------------------------------------
// Pass 2: O_partial[ks] = exp(QK^T) . V'  — SOFTWARE-PIPELINED tiles:
// per 64-k tile, ONE sync interval runs QK(t+1) INTERLEAVED with PV(t)
// (independent MFMA streams; t+1's exp/pack VALU hides under t's PV MFMA),
// and ONE barrier (the cross-wave P handoff).  K/V DMA is remapped so each
// wave stages exactly the LDS region it alone reads -> all staging hazards
// are intra-wave (own lgkmcnt), no extra barriers.  Counted vmcnt(8) in
// steady state: next-V + next-next-K stay in flight across the barrier.
// P-values double-buffered in registers (pwA/pwB, statically indexed).
// 2-way k-split: grid (x=8 (ks,b) [XCD-pinned], y=64 qt), 256 thr,
// 80 KB LDS -> 2 blocks/CU, 32 tiles per block.
// ---------------------------------------------------------------------------
__global__ __launch_bounds__(256, 2) void sdpa_out(
    const ushort_t* __restrict__ Qb, const ushort_t* __restrict__ Kb,
    const ushort_t* __restrict__ VbT,
    float* __restrict__ Op, float* __restrict__ O, int use_partial)
{
    __shared__ ushort_t Kt[2][8192];   // 64 k x 128 dk (swizzled rows, 256B)
    __shared__ ushort_t Vt[2][8192];   // 128 d x 64 k  (atom^(d&7), 128B rows)
    __shared__ ushort_t Pt[2][4096];   // 64 q x 64 k   (atom^(q&7))

    const int g  = blockIdx.x;
    const int qt = blockIdx.y;
    const int ks = g >> 2, b = g & 3;
    const int tid = threadIdx.x;
    const int w = tid >> 6, lane = tid & 63, ln = lane & 15, quad = lane >> 4;
    const int vd2 = lane >> 3, va2 = lane & 7;

    bf16x8 qa[4][4];   // Q tile qt*64..+64 stationary (B-operand frags)
#pragma unroll
    for (int nt = 0; nt < 4; ++nt)
#pragma unroll
        for (int c = 0; c < 4; ++c)
            qa[c][nt] = *(const bf16x8*)(Qb +
                ((size_t)(b * SEQ) + qt * 64 + nt * 16 + ln) * DK +
                (((c * 4 + quad) ^ ln) * 8));

    f32x4 acc[4][2];
#pragma unroll
    for (int i = 0; i < 4; ++i)
#pragma unroll
        for (int j = 0; j < 2; ++j) acc[i][j] = (f32x4){0.f, 0.f, 0.f, 0.f};

    const ushort_t* ksrc = Kb + ((size_t)(b * SEQ) + ks * 2048) * DK;
    const ushort_t* vsrc = VbT + ((size_t)(b * DK)) * SEQ + ks * 2048;

// Per-wave-region staging: wave w writes ONLY the rows it reads.
// K: rows w*16..+15 (16 rows x 256 B); source rows copied position-linear
//    (storage swizzle from cast_qk_sw preserved).
#define DMA_K(BUF, T)                                                          \
    {                                                                          \
        _Pragma("unroll")                                                      \
        for (int j = 0; j < 4; ++j)                                            \
            gld_lds16(ksrc + ((size_t)(T) * 64 + w * 16 + j * 4 + quad) * DK + \
                          ln * 8,                                              \
                      &Kt[BUF][(w * 256 + j * 64) * 8]);                       \
    }
// V: rows w*32..+31 (32 rows x 128 B); source pre-swizzled (pos p of row d
//    holds k-atom p ^ (d & 7)) so B-frag reads are conflict-managed.
#define DMA_V(BUF, T)                                                          \
    {                                                                          \
        _Pragma("unroll")                                                      \
        for (int j = 0; j < 4; ++j)                                            \
            gld_lds16(vsrc + (size_t)(w * 32 + j * 8 + vd2) * SEQ +            \
                          (T) * 64 + ((va2 ^ vd2) * 8),                        \
                      &Vt[BUF][(w * 256 + j * 64) * 8]);                       \
    }

// wave w computes P for its 16-k strip x 64 q; results stay in PW registers
#define QK_COMPUTE(BUF, PW)                                                    \
    {                                                                          \
        bf16x8 kf[4];                                                          \
        _Pragma("unroll")                                                      \
        for (int c = 0; c < 4; ++c)                                            \
            kf[c] = *(const bf16x8*)&Kt[BUF][(w * 16 + ln) * 128 +             \
                                             (((c * 4 + quad) ^ ln) * 8)];     \
        _Pragma("unroll")                                                      \
        for (int nt = 0; nt < 4; ++nt) {                                       \
            f32x4 s = {0.f, 0.f, 0.f, 0.f};                                    \
            __builtin_amdgcn_s_setprio(1);                                     \
            _Pragma("unroll")                                                  \
            for (int c = 0; c < 4; ++c)                                        \
                s = __builtin_amdgcn_mfma_f32_16x16x32_bf16(kf[c], qa[c][nt], s, 0, 0, 0); \
            __builtin_amdgcn_s_setprio(0);                                     \
            PW[nt].x = pk_bf16(__builtin_amdgcn_exp2f(s[0]),                   \
                               __builtin_amdgcn_exp2f(s[1]));                  \
            PW[nt].y = pk_bf16(__builtin_amdgcn_exp2f(s[2]),                   \
                               __builtin_amdgcn_exp2f(s[3]));                  \
        }                                                                      \
    }

#define PT_WRITE(PW, P)                                                        \
    {                                                                          \
        _Pragma("unroll")                                                      \
        for (int nt = 0; nt < 4; ++nt) {                                       \
            const int q = nt * 16 + ln;                                        \
            const int a16 = w * 2 + (quad >> 1);                               \
            *(uint2*)&Pt[P][q * 64 + ((a16 ^ (q & 7)) * 8) + (quad & 1) * 4] = PW[nt]; \
        }                                                                      \
    }

// wave w consumes full 64k P x its 32-d strip of V
#define PV_PHASE(BUF)                                                          \
    {                                                                          \
        _Pragma("unroll")                                                      \
        for (int kc = 0; kc < 2; ++kc) {                                       \
            bf16x8 pa[4], vfr[2];                                              \
            _Pragma("unroll")                                                  \
            for (int qf2 = 0; qf2 < 4; ++qf2)                                  \
                pa[qf2] = *(const bf16x8*)&Pt[BUF][(qf2 * 16 + ln) * 64 +      \
                                    (((kc * 4 + quad) ^ (ln & 7)) * 8)];       \
            _Pragma("unroll")                                                  \
            for (int dt = 0; dt < 2; ++dt)                                     \
                vfr[dt] = *(const bf16x8*)&Vt[BUF][(w * 32 + dt * 16 + ln) * 64 + \
                                    (((kc * 4 + quad) ^ (ln & 7)) * 8)];       \
            __builtin_amdgcn_s_setprio(1);                                     \
            _Pragma("unroll")                                                  \
            for (int qf2 = 0; qf2 < 4; ++qf2)                                  \
                _Pragma("unroll")                                              \
                for (int dt = 0; dt < 2; ++dt)                                 \
                    acc[qf2][dt] = __builtin_amdgcn_mfma_f32_16x16x32_bf16(    \
                        pa[qf2], vfr[dt], acc[qf2][dt], 0, 0, 0);              \
            __builtin_amdgcn_s_setprio(0);                                     \
        }                                                                      \
    }

// one pipelined tile: write P(t); stage K(t+2); wait {V(t),K(t+1)} (leaves
// {V(t+1),K(t+2)} = 8 in flight); barrier; QK(t+1) || PV(t); drain own
// reads; stage V(t+2) into the region just released by PV(t).
#define O_ITER(T, CUR, PWRD, PWWR)                                             \
    {                                                                          \
        PT_WRITE(PWRD, CUR)                                                    \
        DMA_K(CUR, (T) + 2)                                                    \
        asm volatile("s_waitcnt vmcnt(8) lgkmcnt(0)" ::: "memory");            \
        bar_fence();                                                           \
        QK_COMPUTE((CUR) ^ 1, PWWR)                                            \
        PV_PHASE(CUR)                                                          \
        asm volatile("s_waitcnt lgkmcnt(0)" ::: "memory");                     \
        DMA_V(CUR, (T) + 2)                                                    \
    }

    uint2 pwA[4], pwB[4];

    // prologue: stage tiles 0,1; compute QK(0) (own K region -> no barrier)
    DMA_K(0, 0)
    DMA_V(0, 0)
    DMA_K(1, 1)
    DMA_V(1, 1)
    asm volatile("s_waitcnt vmcnt(12)" ::: "memory");   // K(0) landed
    QK_COMPUTE(0, pwA)

    for (int tt = 0; tt < 15; ++tt) {
        const int t0 = 2 * tt;
        O_ITER(t0,     0, pwA, pwB)
        O_ITER(t0 + 1, 1, pwB, pwA)
    }
    // t = 30: no more staging; K(31) must land (leaves V(31) = 4 in flight)
    PT_WRITE(pwA, 0)
    asm volatile("s_waitcnt vmcnt(4) lgkmcnt(0)" ::: "memory");
    bar_fence();
    QK_COMPUTE(1, pwB)
    PV_PHASE(0)
    // t = 31: last tile, PV only
    PT_WRITE(pwB, 1)
    asm volatile("s_waitcnt vmcnt(0) lgkmcnt(0)" ::: "memory");
    bar_fence();
    PV_PHASE(1)
#undef O_ITER
#undef DMA_K
#undef DMA_V
#undef QK_COMPUTE
#undef PT_WRITE
#undef PV_PHASE

    if (use_partial) {
        float* dst = Op + (size_t)ks * ((size_t)BS * SEQ * DK) +
                     ((size_t)(b * SEQ) + qt * 64 + quad * 4) * DK + w * 32 + ln;
#pragma unroll
        for (int qf2 = 0; qf2 < 4; ++qf2)
#pragma unroll
            for (int dt = 0; dt < 2; ++dt)
#pragma unroll
                for (int r = 0; r < 4; ++r)
                    dst[((size_t)(qf2 * 16 + r)) * DK + dt * 16] = acc[qf2][dt][r];
    } else {
#pragma unroll
        for (int qf2 = 0; qf2 < 4; ++qf2)
#pragma unroll
            for (int dt = 0; dt < 2; ++dt)
#pragma unroll
                for (int r = 0; r < 4; ++r)
                    atomicAdd(&O[((size_t)(b * SEQ) + qt * 64 + qf2 * 16 + quad * 4 + r) * DK +
                                 w * 32 + dt * 16 + ln], acc[qf2][dt][r]);
    }
}

// ---------------------------------------------------------------------------
// reduce2: O = sum of 2 k-split partials (float4 per thread).
// ---------------------------------------------------------------------------
__global__ __launch_bounds__(256) void reduce2(
    const float* __restrict__ Op, float* __restrict__ O)
{
    const size_t N = (size_t)BS * SEQ * DK;
    size_t i = ((size_t)blockIdx.x * 256 + threadIdx.x) * 4;
    float4 a0 = *(const float4*)(Op + i);
    float4 a1 = *(const float4*)(Op + N + i);
    float4 r;
    r.x = a0.x + a1.x;
    r.y = a0.y + a1.y;
    r.z = a0.z + a1.z;
    r.w = a0.w + a1.w;
    *(float4*)(O + i) = r;
}

extern "C" void kernel_launch(void* const* d_in, const int* in_sizes, int n_in,
                              void* d_out, int out_size, void* d_ws, size_t ws_size,
                              hipStream_t stream) {
    const float* q = (const float*)d_in[0];
    const float* k = (const float*)d_in[1];
    const float* v = (const float*)d_in[2];
    float* out = (float*)d_out;

    const size_t QKV = (size_t)BS * SEQ * DK;           // 2 M elements
    float*    lp  = (float*)d_ws;                       // 512 KB used
    ushort_t* Qb  = (ushort_t*)((char*)d_ws + (1 << 20));
    ushort_t* Kb  = Qb + QKV;
    ushort_t* VbT = Kb + QKV;
    float*    Op  = (float*)(VbT + QKV);                // 16.8 MB (2 k-splits)

    const size_t need_p = (1u << 20) + 3 * QKV * 2 + 2 * QKV * sizeof(float);

    cast_qk_sw<<<dim3(BS * SEQ * 16 / 256), 256, 0, stream>>>(q, k, Qb, Kb);
    sdpa_lsum  <<<dim3(32, 8, 4), 256, 0, stream>>>(Qb, Kb, lp);
    vb_transpose<<<dim3(64, 4),   256, 0, stream>>>(v, lp, VbT);

    if (ws_size >= need_p) {
        sdpa_out<<<dim3(8, 64), 256, 0, stream>>>(Qb, Kb, VbT, Op, out, 1);
        reduce2<<<dim3(BS * SEQ * DK / 4 / 256), 256, 0, stream>>>(Op, out);
    } else {
        hipMemsetAsync(out, 0, QKV * sizeof(float), stream);
        sdpa_out<<<dim3(8, 64), 256, 0, stream>>>(Qb, Kb, VbT, nullptr, out, 0);
    }
}